// Round 4
// baseline (4205.578 us; speedup 1.0000x reference)
//
#include <hip/hip_runtime.h>

typedef unsigned short u16;
typedef unsigned int   u32;
typedef short short8 __attribute__((ext_vector_type(8)));
typedef float f32x4  __attribute__((ext_vector_type(4)));

#define DEV static __device__ __forceinline__

static constexpr int S_ = 1024;   // seq len
static constexpr int D_ = 256;    // model dim
static constexpr int NR = 4096;   // B*S rows

DEV u16 f2bf(float x) {
    u32 u = __float_as_uint(x);
    return (u16)((u + 0x7FFFu + ((u >> 16) & 1u)) >> 16);
}
DEV float bf2f(u16 s) { return __uint_as_float(((u32)s) << 16); }

// ---------------- elementwise / prep kernels ----------------

__global__ __launch_bounds__(256) void k_fillf(float* __restrict__ o, int n, float v) {
    int i = blockIdx.x * 256 + threadIdx.x;
    if (i < n) o[i] = v;
}

__global__ __launch_bounds__(256) void k_convert(const float* __restrict__ in,
                                                 u16* __restrict__ out, int n4) {
    for (int i = blockIdx.x * 256 + threadIdx.x; i < n4; i += gridDim.x * 256) {
        float4 v = ((const float4*)in)[i];
        ushort4 o; o.x = f2bf(v.x); o.y = f2bf(v.y); o.z = f2bf(v.z); o.w = f2bf(v.w);
        ((ushort4*)out)[i] = o;
    }
}

__global__ __launch_bounds__(256) void k_embed(const int* __restrict__ xx,
                                               const float* __restrict__ cb,
                                               const float* __restrict__ pos,
                                               float* __restrict__ hf, u16* __restrict__ hb) {
    int wid = threadIdx.x >> 6, lane = threadIdx.x & 63;
    int row = blockIdx.x * 4 + wid;         // 0..4095
    int sp = row & (S_ - 1);
    int tok = xx[row];
    float4 c = ((const float4*)(cb + (size_t)tok * D_))[lane];
    float4 p = ((const float4*)(pos + (size_t)sp * D_))[lane];
    float4 s; s.x = c.x + p.x; s.y = c.y + p.y; s.z = c.z + p.z; s.w = c.w + p.w;
    ((float4*)(hf + (size_t)row * D_))[lane] = s;
    ushort4 o; o.x = f2bf(s.x); o.y = f2bf(s.y); o.z = f2bf(s.z); o.w = f2bf(s.w);
    ((ushort4*)(hb + (size_t)row * D_))[lane] = o;
}

__global__ __launch_bounds__(256) void k_addv(const unsigned char* __restrict__ mask,
                                              float* __restrict__ av, float* __restrict__ avz) {
    int i = blockIdx.x * 256 + threadIdx.x;
    if (i < NR) { av[i] = mask[i] ? -2.0e9f : 0.0f; avz[i] = 0.0f; }
}

// residual + layernorm; writes f32 master and bf16 copy
__global__ __launch_bounds__(256) void k_ln(const float* __restrict__ x, const float* __restrict__ y,
                                            const float* __restrict__ gg, const float* __restrict__ bb,
                                            float* __restrict__ of, u16* __restrict__ ob) {
    int wid = threadIdx.x >> 6, lane = threadIdx.x & 63;
    int row = blockIdx.x * 4 + wid;
    float4 xv = ((const float4*)(x + (size_t)row * D_))[lane];
    float4 yv = ((const float4*)(y + (size_t)row * D_))[lane];
    float4 s; s.x = xv.x + yv.x; s.y = xv.y + yv.y; s.z = xv.z + yv.z; s.w = xv.w + yv.w;
    float sum = s.x + s.y + s.z + s.w;
    float sq  = s.x * s.x + s.y * s.y + s.z * s.z + s.w * s.w;
    #pragma unroll
    for (int m = 1; m < 64; m <<= 1) { sum += __shfl_xor(sum, m, 64); sq += __shfl_xor(sq, m, 64); }
    float mean = sum * (1.0f / 256.0f);
    float var  = sq * (1.0f / 256.0f) - mean * mean;
    float rs = rsqrtf(var + 1e-5f);
    float4 gv = ((const float4*)gg)[lane];
    float4 bv = ((const float4*)bb)[lane];
    float4 o;
    o.x = (s.x - mean) * rs * gv.x + bv.x;
    o.y = (s.y - mean) * rs * gv.y + bv.y;
    o.z = (s.z - mean) * rs * gv.z + bv.z;
    o.w = (s.w - mean) * rs * gv.w + bv.w;
    ((float4*)(of + (size_t)row * D_))[lane] = o;
    ushort4 ub; ub.x = f2bf(o.x); ub.y = f2bf(o.y); ub.z = f2bf(o.z); ub.w = f2bf(o.w);
    ((ushort4*)(ob + (size_t)row * D_))[lane] = ub;
}

// ---------------- MFMA GEMM:  C[M,N] = A[M,K](bf16) @ W[N,K]^T(bf16) + bias ----------------
// Reg-staged uint4 loads -> padded linear LDS (stride 72 u16 = 144B). m92/m97-template layout.

template <int BM, int BN, bool RELU, bool OBF16>
__global__ __launch_bounds__(256) void k_gemm(const u16* __restrict__ A, const u16* __restrict__ Bw,
                                              const float* __restrict__ bias,
                                              float* __restrict__ Cf, u16* __restrict__ Cb,
                                              int Nn, int Kk) {
    constexpr int FM = BM / 32, FN = BN / 32;
    constexpr int LDA = 72;   // u16 stride; 144B rows keep 16B alignment, rotate banks by 4/row
    __shared__ __align__(16) u16 As[BM * LDA];
    __shared__ __align__(16) u16 Bs[BN * LDA];
    int tid = threadIdx.x, w = tid >> 6, lane = tid & 63;
    int lr = lane & 15, g = lane >> 4;
    int wm = w >> 1, wn = w & 1;
    int nbn = Nn / BN;
    int m0 = (blockIdx.x / nbn) * BM, n0 = (blockIdx.x % nbn) * BN;
    int trow = tid >> 3, tcol = (tid & 7) << 3;   // 32 rows/pass, 8 u16 per thread

    f32x4 acc[FM][FN] = {};

    for (int kb = 0; kb < Kk; kb += 64) {
        if (kb) __syncthreads();
        #pragma unroll
        for (int r = 0; r < BM / 32; r++) {
            int row = r * 32 + trow;
            uint4 v = *(const uint4*)(A + (size_t)(m0 + row) * Kk + kb + tcol);
            *(uint4*)(As + row * LDA + tcol) = v;
        }
        #pragma unroll
        for (int r = 0; r < BN / 32; r++) {
            int row = r * 32 + trow;
            uint4 v = *(const uint4*)(Bw + (size_t)(n0 + row) * Kk + kb + tcol);
            *(uint4*)(Bs + row * LDA + tcol) = v;
        }
        __syncthreads();
        #pragma unroll
        for (int kk = 0; kk < 2; kk++) {
            short8 af[FM], bfr[FN];
            #pragma unroll
            for (int mi = 0; mi < FM; mi++)
                af[mi] = *(const short8*)(As + (wm * (BM / 2) + mi * 16 + lr) * LDA + kk * 32 + g * 8);
            #pragma unroll
            for (int ni = 0; ni < FN; ni++)
                bfr[ni] = *(const short8*)(Bs + (wn * (BN / 2) + ni * 16 + lr) * LDA + kk * 32 + g * 8);
            #pragma unroll
            for (int mi = 0; mi < FM; mi++)
                #pragma unroll
                for (int ni = 0; ni < FN; ni++)
                    acc[mi][ni] = __builtin_amdgcn_mfma_f32_16x16x32_bf16(af[mi], bfr[ni], acc[mi][ni], 0, 0, 0);
        }
    }

    #pragma unroll
    for (int ni = 0; ni < FN; ni++) {
        int col = n0 + wn * (BN / 2) + ni * 16 + lr;
        float bi = bias[col];
        #pragma unroll
        for (int mi = 0; mi < FM; mi++) {
            #pragma unroll
            for (int jj = 0; jj < 4; jj++) {
                int row = m0 + wm * (BM / 2) + mi * 16 + g * 4 + jj;
                float v = acc[mi][ni][jj] + bi;
                if (RELU) v = fmaxf(v, 0.0f);
                if (OBF16) Cb[(size_t)row * Nn + col] = f2bf(v);
                else       Cf[(size_t)row * Nn + col] = v;
            }
        }
    }
}

// ---------------- NAIVE attention (bisection round): 1 thread = 1 q row ----------------
// grid = B*H*(S/256) = 128 blocks, 256 threads. f32 dots, exact online softmax.

__global__ __launch_bounds__(256) void k_attn_naive(const u16* __restrict__ qp, int qs,
                                                    const u16* __restrict__ kvp, int ks, int koff, int voff,
                                                    const float* __restrict__ addv, u16* __restrict__ out) {
    __shared__ __align__(16) u16 Kt[128 * 32];
    __shared__ __align__(16) u16 Vt[128 * 32];
    __shared__ float At[128];
    int tid = threadIdx.x;
    int blk = blockIdx.x;
    int qc = blk & 3, h = (blk >> 2) & 7, b = blk >> 5;
    int q = qc * 256 + tid;
    const float QS = 0.17677669529663687f;   // 1/sqrt(32)

    float qv[32];
    const u16* qsrc = qp + (size_t)(b * S_ + q) * qs + h * 32;
    #pragma unroll
    for (int i = 0; i < 32; i++) qv[i] = bf2f(qsrc[i]);

    float m = -3.0e38f, l = 0.0f, o[32];
    #pragma unroll
    for (int i = 0; i < 32; i++) o[i] = 0.0f;

    const u16* kbase = kvp + (size_t)(b * S_) * ks;
    for (int t = 0; t < 8; t++) {
        __syncthreads();
        {
            int key = tid >> 1, dh2 = (tid & 1) * 16;
            const u16* sk = kbase + (size_t)(t * 128 + key) * ks + koff + h * 32 + dh2;
            *(uint4*)(Kt + key * 32 + dh2)     = *(const uint4*)sk;
            *(uint4*)(Kt + key * 32 + dh2 + 8) = *(const uint4*)(sk + 8);
            const u16* sv = kbase + (size_t)(t * 128 + key) * ks + voff + h * 32 + dh2;
            *(uint4*)(Vt + key * 32 + dh2)     = *(const uint4*)sv;
            *(uint4*)(Vt + key * 32 + dh2 + 8) = *(const uint4*)(sv + 8);
            if (tid < 128) At[tid] = addv[b * S_ + t * 128 + tid];
        }
        __syncthreads();
        for (int key = 0; key < 128; key++) {
            float s = 0.0f;
            #pragma unroll
            for (int i = 0; i < 32; i++) s = fmaf(qv[i], bf2f(Kt[key * 32 + i]), s);
            s = s * QS + At[key];
            float mn = fmaxf(m, s);
            float corr = __expf(m - mn);
            float p = __expf(s - mn);
            l = l * corr + p;
            #pragma unroll
            for (int i = 0; i < 32; i++) o[i] = o[i] * corr + p * bf2f(Vt[key * 32 + i]);
            m = mn;
        }
    }
    float li = 1.0f / l;
    u16* op = out + (size_t)(b * S_ + q) * 256 + h * 32;
    #pragma unroll
    for (int i = 0; i < 32; i++) op[i] = f2bf(o[i] * li);
}

// ---------------- host orchestration ----------------

extern "C" void kernel_launch(void* const* d_in, const int* in_sizes, int n_in,
                              void* d_out, int out_size, void* d_ws, size_t ws_size,
                              hipStream_t stream) {
    const int* x                = (const int*)d_in[0];
    const unsigned char* mask   = (const unsigned char*)d_in[1];
    const float* codebook       = (const float*)d_in[2];
    const float* pos            = (const float*)d_in[3];
    const float* enc_qkv_w = (const float*)d_in[4];  const float* enc_qkv_b = (const float*)d_in[5];
    const float* enc_out_w = (const float*)d_in[6];  const float* enc_out_b = (const float*)d_in[7];
    const float* enc_ff1_w = (const float*)d_in[8];  const float* enc_ff1_b = (const float*)d_in[9];
    const float* enc_ff2_w = (const float*)d_in[10]; const float* enc_ff2_b = (const float*)d_in[11];
    const float* enc_ln1_g = (const float*)d_in[12]; const float* enc_ln1_b = (const float*)d_in[13];
    const float* enc_ln2_g = (const float*)d_in[14]; const float* enc_ln2_b = (const float*)d_in[15];
    const float* dec_sa_qkv_w = (const float*)d_in[16]; const float* dec_sa_qkv_b = (const float*)d_in[17];
    const float* dec_sa_out_w = (const float*)d_in[18]; const float* dec_sa_out_b = (const float*)d_in[19];
    const float* dec_ca_qkv_w = (const float*)d_in[20]; const float* dec_ca_qkv_b = (const float*)d_in[21];
    const float* dec_ca_out_w = (const float*)d_in[22]; const float* dec_ca_out_b = (const float*)d_in[23];
    const float* dec_ff1_w = (const float*)d_in[24]; const float* dec_ff1_b = (const float*)d_in[25];
    const float* dec_ff2_w = (const float*)d_in[26]; const float* dec_ff2_b = (const float*)d_in[27];
    const float* dec_ln1_g = (const float*)d_in[28]; const float* dec_ln1_b = (const float*)d_in[29];
    const float* dec_ln2_g = (const float*)d_in[30]; const float* dec_ln2_b = (const float*)d_in[31];
    const float* dec_ln3_g = (const float*)d_in[32]; const float* dec_ln3_b = (const float*)d_in[33];

    char* ws = (char*)d_ws; size_t off = 0;
    auto alloc = [&](size_t b) { char* p = ws + off; off += (b + 255) & ~(size_t)255; return p; };

    // bf16 weights (persist whole call)
    u16* w_eqkv  = (u16*)alloc((size_t)786432 * 2);
    u16* w_eout  = (u16*)alloc((size_t)262144 * 2);
    u16* w_eff1  = (u16*)alloc((size_t)2097152 * 2);
    u16* w_eff2  = (u16*)alloc((size_t)2097152 * 2);
    u16* w_dsaq  = (u16*)alloc((size_t)786432 * 2);
    u16* w_dsao  = (u16*)alloc((size_t)262144 * 2);
    u16* w_dcaq  = (u16*)alloc((size_t)786432 * 2);
    u16* w_dcao  = (u16*)alloc((size_t)262144 * 2);
    u16* w_dff1  = (u16*)alloc((size_t)2097152 * 2);
    u16* w_dff2  = (u16*)alloc((size_t)2097152 * 2);
    // persistent activations
    float* h_f   = (float*)alloc((size_t)NR * D_ * 4);
    u16*   h_b   = (u16*)  alloc((size_t)NR * D_ * 2);
    float* ctx_f = (float*)alloc((size_t)NR * D_ * 4);
    u16*   ctx_b = (u16*)  alloc((size_t)NR * D_ * 2);
    float* dd_f  = (float*)alloc((size_t)NR * D_ * 4);
    u16*   dd_b  = (u16*)  alloc((size_t)NR * D_ * 2);
    float* gem_f = (float*)alloc((size_t)NR * 256 * 4);
    u16*   attno = (u16*)  alloc((size_t)NR * 256 * 2);
    float* addv  = (float*)alloc((size_t)NR * 4);
    float* addvz = (float*)alloc((size_t)NR * 4);
    // 16MB scratch, time-shared: enc {qkv_b | ffh_b}; dec {v_b -> qca,kvca | ffh_b}
    u16* scr = (u16*)alloc((size_t)NR * 2048 * 2);
    u16* qkv_b = scr;                      // [4096][768] (enc, dead before ffh use)
    u16* ffh_b = scr;                      // [4096][2048]
    u16* v_b   = scr;                      // [4096][256] (dec, dead before qca)
    u16* qca_b = scr;                      // [4096][256]
    u16* kvca_b = scr + (size_t)NR * 256;  // [4096][512]
    (void)in_sizes; (void)n_in;

    // tripwire: if workspace too small, emit sentinel 1000.0 -> absmax ~1000
    if (off > ws_size) {
        k_fillf<<<(out_size + 255) / 256, 256, 0, stream>>>((float*)d_out, out_size, 1000.0f);
        return;
    }

    auto conv = [&](const float* src, u16* dst, int n) {
        k_convert<<<1024, 256, 0, stream>>>(src, dst, n / 4);
    };
    conv(enc_qkv_w, w_eqkv, 786432);   conv(enc_out_w, w_eout, 262144);
    conv(enc_ff1_w, w_eff1, 2097152);  conv(enc_ff2_w, w_eff2, 2097152);
    conv(dec_sa_qkv_w, w_dsaq, 786432); conv(dec_sa_out_w, w_dsao, 262144);
    conv(dec_ca_qkv_w, w_dcaq, 786432); conv(dec_ca_out_w, w_dcao, 262144);
    conv(dec_ff1_w, w_dff1, 2097152);  conv(dec_ff2_w, w_dff2, 2097152);

    k_addv<<<16, 256, 0, stream>>>(mask, addv, addvz);
    k_embed<<<1024, 256, 0, stream>>>(x, codebook, pos, h_f, h_b);

    // ---- encoder ----
    for (int l = 0; l < 4; l++) {
        const u16* inb = l ? ctx_b : h_b;
        const float* inf = l ? ctx_f : h_f;
        k_gemm<128,128,false,true><<<192, 256, 0, stream>>>(inb, w_eqkv + (size_t)l*196608,
            enc_qkv_b + l*768, nullptr, qkv_b, 768, 256);
        k_attn_naive<<<128, 256, 0, stream>>>(qkv_b, 768, qkv_b, 768, 256, 512, addv, attno);
        k_gemm<64,64,false,false><<<256, 256, 0, stream>>>(attno, w_eout + (size_t)l*65536,
            enc_out_b + l*256, gem_f, nullptr, 256, 256);
        k_ln<<<1024, 256, 0, stream>>>(inf, gem_f, enc_ln1_g + l*256, enc_ln1_b + l*256, ctx_f, ctx_b);
        k_gemm<128,128,true,true><<<512, 256, 0, stream>>>(ctx_b, w_eff1 + (size_t)l*524288,
            enc_ff1_b + l*2048, nullptr, ffh_b, 2048, 256);
        k_gemm<64,64,false,false><<<256, 256, 0, stream>>>(ffh_b, w_eff2 + (size_t)l*524288,
            enc_ff2_b + l*256, gem_f, nullptr, 256, 2048);
        k_ln<<<1024, 256, 0, stream>>>(ctx_f, gem_f, enc_ln2_g + l*256, enc_ln2_b + l*256, ctx_f, ctx_b);
    }

    // ---- decoder ----
    for (int l = 0; l < 4; l++) {
        const u16* inb = l ? dd_b : h_b;
        const float* inf = l ? dd_f : h_f;
        // self-attn degenerates to out_proj(v_proj(x))
        k_gemm<64,64,false,true><<<256, 256, 0, stream>>>(inb, w_dsaq + (size_t)l*196608 + 131072,
            dec_sa_qkv_b + l*768 + 512, nullptr, v_b, 256, 256);
        k_gemm<64,64,false,false><<<256, 256, 0, stream>>>(v_b, w_dsao + (size_t)l*65536,
            dec_sa_out_b + l*256, gem_f, nullptr, 256, 256);
        k_ln<<<1024, 256, 0, stream>>>(inf, gem_f, dec_ln1_g + l*256, dec_ln1_b + l*256, dd_f, dd_b);
        // cross-attn (v_b dead now; qca/kvca reuse scratch)
        k_gemm<64,64,false,true><<<256, 256, 0, stream>>>(dd_b, w_dcaq + (size_t)l*196608,
            dec_ca_qkv_b + l*768, nullptr, qca_b, 256, 256);
        k_gemm<64,64,false,true><<<512, 256, 0, stream>>>(ctx_b, w_dcaq + (size_t)l*196608 + 65536,
            dec_ca_qkv_b + l*768 + 256, nullptr, kvca_b, 512, 256);
        k_attn_naive<<<128, 256, 0, stream>>>(qca_b, 256, kvca_b, 512, 0, 256, addvz, attno);
        k_gemm<64,64,false,false><<<256, 256, 0, stream>>>(attno, w_dcao + (size_t)l*65536,
            dec_ca_out_b + l*256, gem_f, nullptr, 256, 256);
        k_ln<<<1024, 256, 0, stream>>>(dd_f, gem_f, dec_ln2_g + l*256, dec_ln2_b + l*256, dd_f, dd_b);
        // FFN (qca/kvca dead; ffh reuses scratch)
        k_gemm<128,128,true,true><<<512, 256, 0, stream>>>(dd_b, w_dff1 + (size_t)l*524288,
            dec_ff1_b + l*2048, nullptr, ffh_b, 2048, 256);
        k_gemm<64,64,false,false><<<256, 256, 0, stream>>>(ffh_b, w_dff2 + (size_t)l*524288,
            dec_ff2_b + l*256, gem_f, nullptr, 256, 2048);
        // final layer: f32 master goes straight to d_out (reference output dtype is float32)
        k_ln<<<1024, 256, 0, stream>>>(dd_f, gem_f, dec_ln3_g + l*256, dec_ln3_b + l*256,
                                       (l == 3) ? (float*)d_out : dd_f, dd_b);
    }
}

// Round 5
// 762.862 us; speedup vs baseline: 5.5129x; 5.5129x over previous
//
#include <hip/hip_runtime.h>

typedef unsigned short u16;
typedef unsigned int   u32;
typedef short short8 __attribute__((ext_vector_type(8)));
typedef float f32x4  __attribute__((ext_vector_type(4)));

#define DEV static __device__ __forceinline__

static constexpr int S_ = 1024;   // seq len
static constexpr int D_ = 256;    // model dim
static constexpr int NR = 4096;   // B*S rows

DEV u16 f2bf(float x) {
    u32 u = __float_as_uint(x);
    return (u16)((u + 0x7FFFu + ((u >> 16) & 1u)) >> 16);
}
DEV float bf2f(u16 s) { return __uint_as_float(((u32)s) << 16); }

// ---------------- elementwise / prep kernels ----------------

__global__ __launch_bounds__(256) void k_fillf(float* __restrict__ o, int n, float v) {
    int i = blockIdx.x * 256 + threadIdx.x;
    if (i < n) o[i] = v;
}

__global__ __launch_bounds__(256) void k_convert(const float* __restrict__ in,
                                                 u16* __restrict__ out, int n4) {
    for (int i = blockIdx.x * 256 + threadIdx.x; i < n4; i += gridDim.x * 256) {
        float4 v = ((const float4*)in)[i];
        ushort4 o; o.x = f2bf(v.x); o.y = f2bf(v.y); o.z = f2bf(v.z); o.w = f2bf(v.w);
        ((ushort4*)out)[i] = o;
    }
}

__global__ __launch_bounds__(256) void k_embed(const int* __restrict__ xx,
                                               const float* __restrict__ cb,
                                               const float* __restrict__ pos,
                                               float* __restrict__ hf, u16* __restrict__ hb) {
    int wid = threadIdx.x >> 6, lane = threadIdx.x & 63;
    int row = blockIdx.x * 4 + wid;         // 0..4095
    int sp = row & (S_ - 1);
    int tok = xx[row];
    float4 c = ((const float4*)(cb + (size_t)tok * D_))[lane];
    float4 p = ((const float4*)(pos + (size_t)sp * D_))[lane];
    float4 s; s.x = c.x + p.x; s.y = c.y + p.y; s.z = c.z + p.z; s.w = c.w + p.w;
    ((float4*)(hf + (size_t)row * D_))[lane] = s;
    ushort4 o; o.x = f2bf(s.x); o.y = f2bf(s.y); o.z = f2bf(s.z); o.w = f2bf(s.w);
    ((ushort4*)(hb + (size_t)row * D_))[lane] = o;
}

__global__ __launch_bounds__(256) void k_addv(const unsigned char* __restrict__ mask,
                                              float* __restrict__ av, float* __restrict__ avz) {
    int i = blockIdx.x * 256 + threadIdx.x;
    if (i < NR) { av[i] = mask[i] ? -2.0e9f : 0.0f; avz[i] = 0.0f; }
}

// residual + layernorm; writes f32 master and bf16 copy
__global__ __launch_bounds__(256) void k_ln(const float* __restrict__ x, const float* __restrict__ y,
                                            const float* __restrict__ gg, const float* __restrict__ bb,
                                            float* __restrict__ of, u16* __restrict__ ob) {
    int wid = threadIdx.x >> 6, lane = threadIdx.x & 63;
    int row = blockIdx.x * 4 + wid;
    float4 xv = ((const float4*)(x + (size_t)row * D_))[lane];
    float4 yv = ((const float4*)(y + (size_t)row * D_))[lane];
    float4 s; s.x = xv.x + yv.x; s.y = xv.y + yv.y; s.z = xv.z + yv.z; s.w = xv.w + yv.w;
    float sum = s.x + s.y + s.z + s.w;
    float sq  = s.x * s.x + s.y * s.y + s.z * s.z + s.w * s.w;
    #pragma unroll
    for (int m = 1; m < 64; m <<= 1) { sum += __shfl_xor(sum, m, 64); sq += __shfl_xor(sq, m, 64); }
    float mean = sum * (1.0f / 256.0f);
    float var  = sq * (1.0f / 256.0f) - mean * mean;
    float rs = rsqrtf(var + 1e-5f);
    float4 gv = ((const float4*)gg)[lane];
    float4 bv = ((const float4*)bb)[lane];
    float4 o;
    o.x = (s.x - mean) * rs * gv.x + bv.x;
    o.y = (s.y - mean) * rs * gv.y + bv.y;
    o.z = (s.z - mean) * rs * gv.z + bv.z;
    o.w = (s.w - mean) * rs * gv.w + bv.w;
    ((float4*)(of + (size_t)row * D_))[lane] = o;
    ushort4 ub; ub.x = f2bf(o.x); ub.y = f2bf(o.y); ub.z = f2bf(o.z); ub.w = f2bf(o.w);
    ((ushort4*)(ob + (size_t)row * D_))[lane] = ub;
}

// ---------------- MFMA GEMM:  C[M,N] = A[M,K](bf16) @ W[N,K]^T(bf16) + bias ----------------
// Reg-staged uint4 loads -> padded linear LDS (stride 72 u16 = 144B). m92/m97-template layout.

template <int BM, int BN, bool RELU, bool OBF16>
__global__ __launch_bounds__(256) void k_gemm(const u16* __restrict__ A, const u16* __restrict__ Bw,
                                              const float* __restrict__ bias,
                                              float* __restrict__ Cf, u16* __restrict__ Cb,
                                              int Nn, int Kk) {
    constexpr int FM = BM / 32, FN = BN / 32;
    constexpr int LDA = 72;   // u16 stride; 144B rows keep 16B alignment, rotate banks by 4/row
    __shared__ __align__(16) u16 As[BM * LDA];
    __shared__ __align__(16) u16 Bs[BN * LDA];
    int tid = threadIdx.x, w = tid >> 6, lane = tid & 63;
    int lr = lane & 15, g = lane >> 4;
    int wm = w >> 1, wn = w & 1;
    int nbn = Nn / BN;
    int m0 = (blockIdx.x / nbn) * BM, n0 = (blockIdx.x % nbn) * BN;
    int trow = tid >> 3, tcol = (tid & 7) << 3;   // 32 rows/pass, 8 u16 per thread

    f32x4 acc[FM][FN] = {};

    for (int kb = 0; kb < Kk; kb += 64) {
        if (kb) __syncthreads();
        #pragma unroll
        for (int r = 0; r < BM / 32; r++) {
            int row = r * 32 + trow;
            uint4 v = *(const uint4*)(A + (size_t)(m0 + row) * Kk + kb + tcol);
            *(uint4*)(As + row * LDA + tcol) = v;
        }
        #pragma unroll
        for (int r = 0; r < BN / 32; r++) {
            int row = r * 32 + trow;
            uint4 v = *(const uint4*)(Bw + (size_t)(n0 + row) * Kk + kb + tcol);
            *(uint4*)(Bs + row * LDA + tcol) = v;
        }
        __syncthreads();
        #pragma unroll
        for (int kk = 0; kk < 2; kk++) {
            short8 af[FM], bfr[FN];
            #pragma unroll
            for (int mi = 0; mi < FM; mi++)
                af[mi] = *(const short8*)(As + (wm * (BM / 2) + mi * 16 + lr) * LDA + kk * 32 + g * 8);
            #pragma unroll
            for (int ni = 0; ni < FN; ni++)
                bfr[ni] = *(const short8*)(Bs + (wn * (BN / 2) + ni * 16 + lr) * LDA + kk * 32 + g * 8);
            #pragma unroll
            for (int mi = 0; mi < FM; mi++)
                #pragma unroll
                for (int ni = 0; ni < FN; ni++)
                    acc[mi][ni] = __builtin_amdgcn_mfma_f32_16x16x32_bf16(af[mi], bfr[ni], acc[mi][ni], 0, 0, 0);
        }
    }

    #pragma unroll
    for (int ni = 0; ni < FN; ni++) {
        int col = n0 + wn * (BN / 2) + ni * 16 + lr;
        float bi = bias[col];
        #pragma unroll
        for (int mi = 0; mi < FM; mi++) {
            #pragma unroll
            for (int jj = 0; jj < 4; jj++) {
                int row = m0 + wm * (BM / 2) + mi * 16 + g * 4 + jj;
                float v = acc[mi][ni][jj] + bi;
                if (RELU) v = fmaxf(v, 0.0f);
                if (OBF16) Cb[(size_t)row * Nn + col] = f2bf(v);
                else       Cf[(size_t)row * Nn + col] = v;
            }
        }
    }
}

// ---------------- MFMA flash attention (HD=32), bf16 in, bf16 out ----------------
// grid = B*H*16 (qb blocks of 64 rows); 4 waves, 16 q-rows per wave.
// swapped QK^T: S^T = mfma(K,Q) -> lane holds scores for q=lane&15, keys t*16+g*4+jj.
// Padded-linear LDS (stride 136 u16), natural-domain softmax via __expf.

__global__ __launch_bounds__(256) void k_attn(const u16* __restrict__ qp, int qs,
                                              const u16* __restrict__ kvp, int ks, int koff, int voff,
                                              const float* __restrict__ addv, u16* __restrict__ out) {
    __shared__ __align__(16) u16 Kl[128 * 32];       // [key][d] linear
    __shared__ __align__(16) u16 VTl[32 * 136];      // [d][key] padded linear
    __shared__ __align__(16) u16 Pl[4 * 16 * 136];   // per-wave [q][key] padded linear
    __shared__ float Al[128];

    int tid = threadIdx.x, w = tid >> 6, lane = tid & 63;
    int lr = lane & 15, g = lane >> 4;
    int blk = blockIdx.x;
    int qb = blk & 15, h = (blk >> 4) & 7, b = blk >> 7;
    int q0 = qb * 64 + w * 16;
    const float QS = 0.17677669529663687f;   // 1/sqrt(32)

    short8 qf = *(const short8*)(qp + (size_t)(b * S_ + q0 + lr) * qs + h * 32 + g * 8);

    f32x4 o0 = {0.f, 0.f, 0.f, 0.f}, o1 = {0.f, 0.f, 0.f, 0.f};
    float m_run = -3.0e38f, l_run = 0.0f;
    float sreg[8][4];
    u16* Pw = Pl + w * 16 * 136;

    int key_t = tid >> 1, dh = (tid & 1) * 16;    // staging roles
    const u16* kbase = kvp + (size_t)(b * S_) * ks;

    for (int kb = 0; kb < 8; kb++) {
        // ---- stage K [128][32] linear, V^T [32][136] padded, addv ----
        {
            const u16* srck = kbase + (size_t)(kb * 128 + key_t) * ks + koff + h * 32 + dh;
            uint4 a0 = *(const uint4*)srck;
            uint4 a1 = *(const uint4*)(srck + 8);
            *(uint4*)(Kl + key_t * 32 + dh) = a0;
            *(uint4*)(Kl + key_t * 32 + dh + 8) = a1;
            const u16* srcv = kbase + (size_t)(kb * 128 + key_t) * ks + voff + h * 32 + dh;
            union { uint4 v[2]; u16 s[16]; } vu;
            vu.v[0] = *(const uint4*)srcv; vu.v[1] = *(const uint4*)(srcv + 8);
            #pragma unroll
            for (int i = 0; i < 16; i++) VTl[(dh + i) * 136 + key_t] = vu.s[i];
            if (tid < 128) Al[tid] = addv[b * S_ + kb * 128 + tid];
        }
        __syncthreads();

        // ---- QK^T (swapped): lane holds scores for q=lr, keys t*16+g*4+jj ----
        #pragma unroll
        for (int t = 0; t < 8; t++) {
            short8 kf = *(const short8*)(Kl + (t * 16 + lr) * 32 + g * 8);
            f32x4 z = {0.f, 0.f, 0.f, 0.f};
            f32x4 st = __builtin_amdgcn_mfma_f32_16x16x32_bf16(kf, qf, z, 0, 0, 0);
            #pragma unroll
            for (int jj = 0; jj < 4; jj++) sreg[t][jj] = st[jj] * QS + Al[t * 16 + g * 4 + jj];
        }

        // ---- online softmax (natural domain) ----
        float mb = -3.0e38f;
        #pragma unroll
        for (int t = 0; t < 8; t++)
            #pragma unroll
            for (int jj = 0; jj < 4; jj++) mb = fmaxf(mb, sreg[t][jj]);
        mb = fmaxf(mb, __shfl_xor(mb, 16, 64));
        mb = fmaxf(mb, __shfl_xor(mb, 32, 64));
        float mnew = fmaxf(m_run, mb);
        float sc = __expf(m_run - mnew);
        float ls = 0.f;
        #pragma unroll
        for (int t = 0; t < 8; t++)
            #pragma unroll
            for (int jj = 0; jj < 4; jj++) {
                float p = __expf(sreg[t][jj] - mnew);
                sreg[t][jj] = p; ls += p;
            }
        ls += __shfl_xor(ls, 16, 64); ls += __shfl_xor(ls, 32, 64);
        l_run = l_run * sc + ls; m_run = mnew;
        #pragma unroll
        for (int jj = 0; jj < 4; jj++) {
            float scj = __shfl(sc, 20 * g + jj, 64);   // lane 16g + (4g+jj): lr' == 4g+jj
            o0[jj] *= scj; o1[jj] *= scj;
        }

        // ---- write P[q][key] (uint2 = 4 consecutive keys) ----
        #pragma unroll
        for (int t = 0; t < 8; t++) {
            u32 u0 = (u32)f2bf(sreg[t][0]) | ((u32)f2bf(sreg[t][1]) << 16);
            u32 u1 = (u32)f2bf(sreg[t][2]) | ((u32)f2bf(sreg[t][3]) << 16);
            *(uint2*)(Pw + lr * 136 + t * 16 + g * 4) = make_uint2(u0, u1);
        }

        // ---- PV: O += P @ V  (A = P[q][k], B = V[k][d] from VT) ----
        #pragma unroll
        for (int c = 0; c < 4; c++) {
            short8 pa = *(const short8*)(Pw + lr * 136 + c * 32 + g * 8);
            short8 v0 = *(const short8*)(VTl + lr * 136 + c * 32 + g * 8);
            short8 v1 = *(const short8*)(VTl + (16 + lr) * 136 + c * 32 + g * 8);
            o0 = __builtin_amdgcn_mfma_f32_16x16x32_bf16(pa, v0, o0, 0, 0, 0);
            o1 = __builtin_amdgcn_mfma_f32_16x16x32_bf16(pa, v1, o1, 0, 0, 0);
        }
        __syncthreads();
    }

    float li = 1.0f / l_run;
    #pragma unroll
    for (int jj = 0; jj < 4; jj++) {
        float lij = __shfl(li, 20 * g + jj, 64);
        int r = q0 + g * 4 + jj;
        u16* op = out + (size_t)(b * S_ + r) * 256 + h * 32;
        op[lr]      = f2bf(o0[jj] * lij);
        op[16 + lr] = f2bf(o1[jj] * lij);
    }
}

// ---------------- host orchestration ----------------

extern "C" void kernel_launch(void* const* d_in, const int* in_sizes, int n_in,
                              void* d_out, int out_size, void* d_ws, size_t ws_size,
                              hipStream_t stream) {
    const int* x                = (const int*)d_in[0];
    const unsigned char* mask   = (const unsigned char*)d_in[1];
    const float* codebook       = (const float*)d_in[2];
    const float* pos            = (const float*)d_in[3];
    const float* enc_qkv_w = (const float*)d_in[4];  const float* enc_qkv_b = (const float*)d_in[5];
    const float* enc_out_w = (const float*)d_in[6];  const float* enc_out_b = (const float*)d_in[7];
    const float* enc_ff1_w = (const float*)d_in[8];  const float* enc_ff1_b = (const float*)d_in[9];
    const float* enc_ff2_w = (const float*)d_in[10]; const float* enc_ff2_b = (const float*)d_in[11];
    const float* enc_ln1_g = (const float*)d_in[12]; const float* enc_ln1_b = (const float*)d_in[13];
    const float* enc_ln2_g = (const float*)d_in[14]; const float* enc_ln2_b = (const float*)d_in[15];
    const float* dec_sa_qkv_w = (const float*)d_in[16]; const float* dec_sa_qkv_b = (const float*)d_in[17];
    const float* dec_sa_out_w = (const float*)d_in[18]; const float* dec_sa_out_b = (const float*)d_in[19];
    const float* dec_ca_qkv_w = (const float*)d_in[20]; const float* dec_ca_qkv_b = (const float*)d_in[21];
    const float* dec_ca_out_w = (const float*)d_in[22]; const float* dec_ca_out_b = (const float*)d_in[23];
    const float* dec_ff1_w = (const float*)d_in[24]; const float* dec_ff1_b = (const float*)d_in[25];
    const float* dec_ff2_w = (const float*)d_in[26]; const float* dec_ff2_b = (const float*)d_in[27];
    const float* dec_ln1_g = (const float*)d_in[28]; const float* dec_ln1_b = (const float*)d_in[29];
    const float* dec_ln2_g = (const float*)d_in[30]; const float* dec_ln2_b = (const float*)d_in[31];
    const float* dec_ln3_g = (const float*)d_in[32]; const float* dec_ln3_b = (const float*)d_in[33];

    char* ws = (char*)d_ws; size_t off = 0;
    auto alloc = [&](size_t b) { char* p = ws + off; off += (b + 255) & ~(size_t)255; return p; };

    // bf16 weights (persist whole call)
    u16* w_eqkv  = (u16*)alloc((size_t)786432 * 2);
    u16* w_eout  = (u16*)alloc((size_t)262144 * 2);
    u16* w_eff1  = (u16*)alloc((size_t)2097152 * 2);
    u16* w_eff2  = (u16*)alloc((size_t)2097152 * 2);
    u16* w_dsaq  = (u16*)alloc((size_t)786432 * 2);
    u16* w_dsao  = (u16*)alloc((size_t)262144 * 2);
    u16* w_dcaq  = (u16*)alloc((size_t)786432 * 2);
    u16* w_dcao  = (u16*)alloc((size_t)262144 * 2);
    u16* w_dff1  = (u16*)alloc((size_t)2097152 * 2);
    u16* w_dff2  = (u16*)alloc((size_t)2097152 * 2);
    // persistent activations
    float* h_f   = (float*)alloc((size_t)NR * D_ * 4);
    u16*   h_b   = (u16*)  alloc((size_t)NR * D_ * 2);
    float* ctx_f = (float*)alloc((size_t)NR * D_ * 4);
    u16*   ctx_b = (u16*)  alloc((size_t)NR * D_ * 2);
    float* dd_f  = (float*)alloc((size_t)NR * D_ * 4);
    u16*   dd_b  = (u16*)  alloc((size_t)NR * D_ * 2);
    float* gem_f = (float*)alloc((size_t)NR * 256 * 4);
    u16*   attno = (u16*)  alloc((size_t)NR * 256 * 2);
    float* addv  = (float*)alloc((size_t)NR * 4);
    float* addvz = (float*)alloc((size_t)NR * 4);
    // 16MB scratch, time-shared: enc {qkv_b | ffh_b}; dec {v_b -> qca,kvca | ffh_b}
    u16* scr = (u16*)alloc((size_t)NR * 2048 * 2);
    u16* qkv_b = scr;                      // [4096][768] (enc, dead before ffh use)
    u16* ffh_b = scr;                      // [4096][2048]
    u16* v_b   = scr;                      // [4096][256] (dec, dead before qca)
    u16* qca_b = scr;                      // [4096][256]
    u16* kvca_b = scr + (size_t)NR * 256;  // [4096][512]
    (void)in_sizes; (void)n_in;

    // tripwire: if workspace too small, emit sentinel 1000.0 -> absmax ~1000
    if (off > ws_size) {
        k_fillf<<<(out_size + 255) / 256, 256, 0, stream>>>((float*)d_out, out_size, 1000.0f);
        return;
    }

    auto conv = [&](const float* src, u16* dst, int n) {
        k_convert<<<1024, 256, 0, stream>>>(src, dst, n / 4);
    };
    conv(enc_qkv_w, w_eqkv, 786432);   conv(enc_out_w, w_eout, 262144);
    conv(enc_ff1_w, w_eff1, 2097152);  conv(enc_ff2_w, w_eff2, 2097152);
    conv(dec_sa_qkv_w, w_dsaq, 786432); conv(dec_sa_out_w, w_dsao, 262144);
    conv(dec_ca_qkv_w, w_dcaq, 786432); conv(dec_ca_out_w, w_dcao, 262144);
    conv(dec_ff1_w, w_dff1, 2097152);  conv(dec_ff2_w, w_dff2, 2097152);

    k_addv<<<16, 256, 0, stream>>>(mask, addv, addvz);
    k_embed<<<1024, 256, 0, stream>>>(x, codebook, pos, h_f, h_b);

    // ---- encoder ----
    for (int l = 0; l < 4; l++) {
        const u16* inb = l ? ctx_b : h_b;
        const float* inf = l ? ctx_f : h_f;
        k_gemm<128,128,false,true><<<192, 256, 0, stream>>>(inb, w_eqkv + (size_t)l*196608,
            enc_qkv_b + l*768, nullptr, qkv_b, 768, 256);
        k_attn<<<512, 256, 0, stream>>>(qkv_b, 768, qkv_b, 768, 256, 512, addv, attno);
        k_gemm<64,64,false,false><<<256, 256, 0, stream>>>(attno, w_eout + (size_t)l*65536,
            enc_out_b + l*256, gem_f, nullptr, 256, 256);
        k_ln<<<1024, 256, 0, stream>>>(inf, gem_f, enc_ln1_g + l*256, enc_ln1_b + l*256, ctx_f, ctx_b);
        k_gemm<128,128,true,true><<<512, 256, 0, stream>>>(ctx_b, w_eff1 + (size_t)l*524288,
            enc_ff1_b + l*2048, nullptr, ffh_b, 2048, 256);
        k_gemm<64,64,false,false><<<256, 256, 0, stream>>>(ffh_b, w_eff2 + (size_t)l*524288,
            enc_ff2_b + l*256, gem_f, nullptr, 256, 2048);
        k_ln<<<1024, 256, 0, stream>>>(ctx_f, gem_f, enc_ln2_g + l*256, enc_ln2_b + l*256, ctx_f, ctx_b);
    }

    // ---- decoder ----
    for (int l = 0; l < 4; l++) {
        const u16* inb = l ? dd_b : h_b;
        const float* inf = l ? dd_f : h_f;
        // self-attn degenerates to out_proj(v_proj(x))
        k_gemm<64,64,false,true><<<256, 256, 0, stream>>>(inb, w_dsaq + (size_t)l*196608 + 131072,
            dec_sa_qkv_b + l*768 + 512, nullptr, v_b, 256, 256);
        k_gemm<64,64,false,false><<<256, 256, 0, stream>>>(v_b, w_dsao + (size_t)l*65536,
            dec_sa_out_b + l*256, gem_f, nullptr, 256, 256);
        k_ln<<<1024, 256, 0, stream>>>(inf, gem_f, dec_ln1_g + l*256, dec_ln1_b + l*256, dd_f, dd_b);
        // cross-attn (v_b dead now; qca/kvca reuse scratch)
        k_gemm<64,64,false,true><<<256, 256, 0, stream>>>(dd_b, w_dcaq + (size_t)l*196608,
            dec_ca_qkv_b + l*768, nullptr, qca_b, 256, 256);
        k_gemm<64,64,false,true><<<512, 256, 0, stream>>>(ctx_b, w_dcaq + (size_t)l*196608 + 65536,
            dec_ca_qkv_b + l*768 + 256, nullptr, kvca_b, 512, 256);
        k_attn<<<512, 256, 0, stream>>>(qca_b, 256, kvca_b, 512, 0, 256, addvz, attno);
        k_gemm<64,64,false,false><<<256, 256, 0, stream>>>(attno, w_dcao + (size_t)l*65536,
            dec_ca_out_b + l*256, gem_f, nullptr, 256, 256);
        k_ln<<<1024, 256, 0, stream>>>(dd_f, gem_f, dec_ln2_g + l*256, dec_ln2_b + l*256, dd_f, dd_b);
        // FFN (qca/kvca dead; ffh reuses scratch)
        k_gemm<128,128,true,true><<<512, 256, 0, stream>>>(dd_b, w_dff1 + (size_t)l*524288,
            dec_ff1_b + l*2048, nullptr, ffh_b, 2048, 256);
        k_gemm<64,64,false,false><<<256, 256, 0, stream>>>(ffh_b, w_dff2 + (size_t)l*524288,
            dec_ff2_b + l*256, gem_f, nullptr, 256, 2048);
        // final layer: f32 master goes straight to d_out (reference output dtype is float32)
        k_ln<<<1024, 256, 0, stream>>>(dd_f, gem_f, dec_ln3_g + l*256, dec_ln3_b + l*256,
                                       (l == 3) ? (float*)d_out : dd_f, dd_b);
    }
}